// Round 4
// baseline (127.537 us; speedup 1.0000x reference)
//
#include <hip/hip_runtime.h>
#include <math.h>

#define DD 128
#define HH 128
#define WW 128
#define NN (DD*HH*WW)
#define DJ 127

// workspace layout: [slots: doubles][bwd interleaved float4 volume]
#define NB_LNCC 4096
#define NB_FUSED 4096
#define LOFF 0
#define GOFF (NB_LNCC)
#define JOFF (NB_LNCC + NB_FUSED)
#define IOFF (NB_LNCC + 2*NB_FUSED)
#define NSLOTS (NB_LNCC + 3*NB_FUSED)            // 16384 doubles = 128 KiB
#define BWDI_OFF ((size_t)NSLOTS * 8)            // 16B aligned
#define WS_NEED (BWDI_OFF + (size_t)NN * 16)

// ---------- small helpers ----------
__device__ __forceinline__ double wave_reduce(double v) {
    #pragma unroll
    for (int o = 32; o > 0; o >>= 1) v += __shfl_down(v, o);
    return v;
}

template <int NWAVES>
__device__ __forceinline__ double block_reduce(double v, double* red, int tid) {
    v = wave_reduce(v);
    int wid = tid >> 6, lane = tid & 63;
    __syncthreads();
    if (lane == 0) red[wid] = v;
    __syncthreads();
    double x = 0.0;
    if (tid == 0) {
        #pragma unroll
        for (int w = 0; w < NWAVES; w++) x += red[w];
    }
    return x;
}

__device__ __forceinline__ float4 add4(float4 a, float4 b) {
    return make_float4(a.x + b.x, a.y + b.y, a.z + b.z, a.w + b.w);
}

__device__ __forceinline__ float jac_term(const float* dz_, const float* dy_, const float* dx_) {
    float a00 = 1.f + dz_[0], a01 = dy_[0], a02 = dx_[0];
    float a10 = dz_[1], a11 = 1.f + dy_[1], a12 = dx_[1];
    float a20 = dz_[2], a21 = dy_[2], a22 = 1.f + dx_[2];
    float det = a00 * (a11 * a22 - a12 * a21)
              - a01 * (a10 * a22 - a12 * a20)
              + a02 * (a10 * a21 - a11 * a20);
    if (isnan(det)) det = 0.f;
    else if (isinf(det)) det = det > 0.f ? 1000.f : -1000.f;
    float neg = -det;
    return neg > 0.f ? neg : 0.f;
}

// ---------- 1) LNCC (separable box filter, vector LDS) + embedded bwd interleave ----------
// Tile: 8^3 outputs, 12^3 window footprint. 512 threads.
// x-pass reads GLOBAL directly (3 aligned float4 per half-row), writes 5 moment fields to LDS.
__global__ __launch_bounds__(512) void lncc_kernel(const float* __restrict__ src,
                                                   const float* __restrict__ tgt,
                                                   const float* __restrict__ bwd,
                                                   float4* __restrict__ bwdi,
                                                   double* __restrict__ ws) {
    __shared__ __align__(16) float F1[5][12 * 12 * 8];   // x-summed moments
    __shared__ __align__(16) float F2[5][12 * 8 * 8];    // xy-summed moments
    __shared__ double red[8];
    const int tid = threadIdx.x;
    const int bid = blockIdx.x;
    const int bx = (bid & 15) * 8, by = ((bid >> 4) & 15) * 8, bz = (bid >> 8) * 8;

    // ---- embedded channel-interleave of bwd (1 voxel/thread) ----
    if (bwdi) {
        int i = bid * 512 + tid;
        bwdi[i] = make_float4(bwd[i], bwd[NN + i], bwd[2 * NN + i], 0.f);
    }

    // ---- x-pass: one half-row (4 outputs) per thread, 288 tasks ----
    if (tid < 288) {
        const int h = tid & 1;
        const int row = tid >> 1;
        const int ly = row % 12, lz = row / 12;
        const int gy = by + ly - 2, gz = bz + lz - 2;
        const bool rowok = (gy >= 0 && gy < HH && gz >= 0 && gz < DD);
        const int rowbase = (gz * HH + gy) * WW;
        const int w0 = bx + h * 4 - 4;            // aligned float4 window start

        float4 lsv[3], ltv[3];
        #pragma unroll
        for (int p = 0; p < 3; p++) {
            int gx = w0 + 4 * p;
            if (rowok && gx >= 0 && gx <= WW - 4) {
                lsv[p] = *(const float4*)(src + rowbase + gx);
                ltv[p] = *(const float4*)(tgt + rowbase + gx);
            } else {
                lsv[p] = make_float4(0.f, 0.f, 0.f, 0.f);
                ltv[p] = make_float4(0.f, 0.f, 0.f, 0.f);
            }
        }
        const float* ls = (const float*)lsv;   // 12 values, static-indexed below
        const float* lt = (const float*)ltv;

        float o[5][4];
        #pragma unroll
        for (int k = 0; k < 4; k++) {
            float s1 = 0.f, t1 = 0.f, s2 = 0.f, t2 = 0.f, st = 0.f;
            #pragma unroll
            for (int d = 0; d < 5; d++) {
                float a = ls[k + d + 2], b = lt[k + d + 2];
                s1 += a; t1 += b;
                s2 = fmaf(a, a, s2); t2 = fmaf(b, b, t2); st = fmaf(a, b, st);
            }
            o[0][k] = s1; o[1][k] = t1; o[2][k] = s2; o[3][k] = t2; o[4][k] = st;
        }
        const int obase = (lz * 12 + ly) * 8 + h * 4;
        #pragma unroll
        for (int f = 0; f < 5; f++)
            *(float4*)&F1[f][obase] = make_float4(o[f][0], o[f][1], o[f][2], o[f][3]);
    }
    __syncthreads();

    // ---- y-pass: 4 outputs per thread, 192 tasks ----
    if (tid < 192) {
        const int h = tid & 1;
        const int r = tid >> 1;
        const int oy = r & 7, lz = r >> 3;
        float4 a0 = make_float4(0.f, 0.f, 0.f, 0.f), a1 = a0, a2 = a0, a3 = a0, a4 = a0;
        #pragma unroll
        for (int dy = 0; dy < 5; dy++) {
            const int j = (lz * 12 + oy + dy) * 8 + h * 4;
            a0 = add4(a0, *(const float4*)&F1[0][j]);
            a1 = add4(a1, *(const float4*)&F1[1][j]);
            a2 = add4(a2, *(const float4*)&F1[2][j]);
            a3 = add4(a3, *(const float4*)&F1[3][j]);
            a4 = add4(a4, *(const float4*)&F1[4][j]);
        }
        const int jo = (lz * 8 + oy) * 8 + h * 4;
        *(float4*)&F2[0][jo] = a0;
        *(float4*)&F2[1][jo] = a1;
        *(float4*)&F2[2][jo] = a2;
        *(float4*)&F2[3][jo] = a3;
        *(float4*)&F2[4][jo] = a4;
    }
    __syncthreads();

    // ---- z-pass + lncc: 4 voxels per thread, 128 tasks ----
    double lsum = 0.0;
    if (tid < 128) {
        const int h = tid & 1;
        const int r = tid >> 1;
        const int oy = r & 7, oz = r >> 3;
        float A[5][4];
        #pragma unroll
        for (int f = 0; f < 5; f++) { A[f][0] = A[f][1] = A[f][2] = A[f][3] = 0.f; }
        #pragma unroll
        for (int dz = 0; dz < 5; dz++) {
            const int j = ((oz + dz) * 8 + oy) * 8 + h * 4;
            #pragma unroll
            for (int f = 0; f < 5; f++) {
                float4 q = *(const float4*)&F2[f][j];
                A[f][0] += q.x; A[f][1] += q.y; A[f][2] += q.z; A[f][3] += q.w;
            }
        }
        const float inv125 = 1.f / 125.f;
        #pragma unroll
        for (int k = 0; k < 4; k++) {
            float sm = A[0][k] * inv125, tm = A[1][k] * inv125;
            float sv = A[2][k] * inv125 - sm * sm;
            float tv = A[3][k] * inv125 - tm * tm;
            float cross = A[4][k] * inv125 - sm * tm;
            float l = cross * cross / (sv * tv + 1e-5f);
            lsum += (double)l;
        }
    }
    double tot = block_reduce<8>(lsum, red, tid);
    if (tid == 0) ws[LOFF + bid] = tot;
}

// ---------- 2) fused grad + jac + inverse-consistency, 2 voxels/thread ----------
__global__ __launch_bounds__(256, 8) void fused2_kernel(const float* __restrict__ fwd,
                                                        const float4* __restrict__ bwdi,
                                                        double* __restrict__ ws) {
    __shared__ double red[4];
    double accG = 0.0, accJ = 0.0, accI = 0.0;

    const int pr = blockIdx.x * 256 + threadIdx.x;   // pair id
    const int t2 = pr * 2;
    const int x = t2 & 127; int rr = t2 >> 7; const int y = rr & 127; const int z = rr >> 7;
    const bool hy = (y < HH - 1), hz = (z < DD - 1);

    float va[3][2];
    float d0x[3], d0y[3], d0z[3], d1x[3], d1y[3], d1z[3];
    #pragma unroll
    for (int c = 0; c < 3; c++) {
        const float* p = fwd + c * NN + t2;
        float2 q = *(const float2*)p;
        float x2 = (x < WW - 2) ? p[2] : 0.f;
        float2 qy = hy ? *(const float2*)(p + WW) : make_float2(0.f, 0.f);
        float2 qz = hz ? *(const float2*)(p + WW * HH) : make_float2(0.f, 0.f);
        va[c][0] = q.x; va[c][1] = q.y;
        d0x[c] = q.y - q.x;                         // x <= 126, always valid
        d1x[c] = (x < WW - 2) ? (x2 - q.y) : 0.f;
        d0y[c] = hy ? (qy.x - q.x) : 0.f;
        d1y[c] = hy ? (qy.y - q.y) : 0.f;
        d0z[c] = hz ? (qz.x - q.x) : 0.f;
        d1z[c] = hz ? (qz.y - q.y) : 0.f;
    }

    // grad3d L2 (both voxels)
    {
        float g = 0.f;
        #pragma unroll
        for (int c = 0; c < 3; c++) {
            g = fmaf(d0x[c], d0x[c], g); g = fmaf(d0y[c], d0y[c], g); g = fmaf(d0z[c], d0z[c], g);
            g = fmaf(d1x[c], d1x[c], g); g = fmaf(d1y[c], d1y[c], g); g = fmaf(d1z[c], d1z[c], g);
        }
        accG += (double)g;
    }

    // negative Jacobian (interior only)
    if (hy && hz) {
        accJ += (double)jac_term(d0z, d0y, d0x);         // voxel 0: x <= 126 < 127
        if (x < WW - 2) accJ += (double)jac_term(d1z, d1y, d1x);
    }

    // inverse consistency per voxel
    #pragma unroll
    for (int j = 0; j < 2; j++) {
        const int xj = x + j;
        float v0 = va[0][j], v1 = va[1][j], v2 = va[2][j];
        float cz = fminf(fmaxf((float)z + v0, 0.f), (float)(DD - 1));
        float cy = fminf(fmaxf((float)y + v1, 0.f), (float)(HH - 1));
        float cx = fminf(fmaxf((float)xj + v2, 0.f), (float)(WW - 1));
        float z0f = floorf(cz), y0f = floorf(cy), x0f = floorf(cx);
        float fz = cz - z0f, fy = cy - y0f, fx = cx - x0f;
        int z0 = (int)z0f, y0 = (int)y0f, x0 = (int)x0f;
        int z1 = min(z0 + 1, DD - 1), y1 = min(y0 + 1, HH - 1), x1 = min(x0 + 1, WW - 1);
        int b00 = (z0 * HH + y0) * WW, b01 = (z0 * HH + y1) * WW;
        int b10 = (z1 * HH + y0) * WW, b11 = (z1 * HH + y1) * WW;
        float4 C000 = bwdi[b00 + x0], C001 = bwdi[b00 + x1];
        float4 C010 = bwdi[b01 + x0], C011 = bwdi[b01 + x1];
        float4 C100 = bwdi[b10 + x0], C101 = bwdi[b10 + x1];
        float4 C110 = bwdi[b11 + x0], C111 = bwdi[b11 + x1];
        float w000 = (1.f - fz) * (1.f - fy) * (1.f - fx);
        float w001 = (1.f - fz) * (1.f - fy) * fx;
        float w010 = (1.f - fz) * fy * (1.f - fx);
        float w011 = (1.f - fz) * fy * fx;
        float w100 = fz * (1.f - fy) * (1.f - fx);
        float w101 = fz * (1.f - fy) * fx;
        float w110 = fz * fy * (1.f - fx);
        float w111 = fz * fy * fx;
        float c0 = v0 + w000 * C000.x + w001 * C001.x + w010 * C010.x + w011 * C011.x
                      + w100 * C100.x + w101 * C101.x + w110 * C110.x + w111 * C111.x;
        float c1 = v1 + w000 * C000.y + w001 * C001.y + w010 * C010.y + w011 * C011.y
                      + w100 * C100.y + w101 * C101.y + w110 * C110.y + w111 * C111.y;
        float c2 = v2 + w000 * C000.z + w001 * C001.z + w010 * C010.z + w011 * C011.z
                      + w100 * C100.z + w101 * C101.z + w110 * C110.z + w111 * C111.z;
        accI += (double)(c0 * c0 + c1 * c1 + c2 * c2);
    }

    double tG = block_reduce<4>(accG, red, threadIdx.x);
    double tJ = block_reduce<4>(accJ, red, threadIdx.x);
    double tI = block_reduce<4>(accI, red, threadIdx.x);
    if (threadIdx.x == 0) {
        ws[GOFF + blockIdx.x] = tG;
        ws[JOFF + blockIdx.x] = tJ;
        ws[IOFF + blockIdx.x] = tI;
    }
}

// ---------- 2b) fallback fused kernel (scalar gathers from planar bwd) ----------
__global__ __launch_bounds__(256) void fused_fallback(const float* __restrict__ fwd,
                                                      const float* __restrict__ bwd,
                                                      double* __restrict__ ws) {
    __shared__ double red[4];
    double accG = 0.0, accJ = 0.0, accI = 0.0;

    for (int idx = blockIdx.x * 256 + threadIdx.x; idx < NN; idx += gridDim.x * 256) {
        const int x = idx % WW; int r = idx / WW; const int y = r % HH; const int z = r / HH;
        const bool hx = (x < WW - 1), hy = (y < HH - 1), hz = (z < DD - 1);

        float v[3], ddx[3], ddy[3], ddz[3];
        #pragma unroll
        for (int c = 0; c < 3; c++) {
            const float* p = fwd + c * NN + idx;
            float vv = p[0];
            v[c]   = vv;
            ddx[c] = hx ? (p[1] - vv) : 0.f;
            ddy[c] = hy ? (p[WW] - vv) : 0.f;
            ddz[c] = hz ? (p[HH * WW] - vv) : 0.f;
        }
        float g = 0.f;
        #pragma unroll
        for (int c = 0; c < 3; c++)
            g = fmaf(ddz[c], ddz[c], fmaf(ddy[c], ddy[c], fmaf(ddx[c], ddx[c], g)));
        accG += (double)g;

        if (hx && hy && hz) accJ += (double)jac_term(ddz, ddy, ddx);
        {
            float cz = fminf(fmaxf((float)z + v[0], 0.f), (float)(DD - 1));
            float cy = fminf(fmaxf((float)y + v[1], 0.f), (float)(HH - 1));
            float cx = fminf(fmaxf((float)x + v[2], 0.f), (float)(WW - 1));
            float z0f = floorf(cz), y0f = floorf(cy), x0f = floorf(cx);
            float fz = cz - z0f, fy = cy - y0f, fx = cx - x0f;
            int z0 = (int)z0f, y0 = (int)y0f, x0 = (int)x0f;
            int z1 = min(z0 + 1, DD - 1), y1 = min(y0 + 1, HH - 1), x1 = min(x0 + 1, WW - 1);
            int i000 = (z0 * HH + y0) * WW + x0, i001 = (z0 * HH + y0) * WW + x1;
            int i010 = (z0 * HH + y1) * WW + x0, i011 = (z0 * HH + y1) * WW + x1;
            int i100 = (z1 * HH + y0) * WW + x0, i101 = (z1 * HH + y0) * WW + x1;
            int i110 = (z1 * HH + y1) * WW + x0, i111 = (z1 * HH + y1) * WW + x1;
            float w000 = (1.f - fz) * (1.f - fy) * (1.f - fx);
            float w001 = (1.f - fz) * (1.f - fy) * fx;
            float w010 = (1.f - fz) * fy * (1.f - fx);
            float w011 = (1.f - fz) * fy * fx;
            float w100 = fz * (1.f - fy) * (1.f - fx);
            float w101 = fz * (1.f - fy) * fx;
            float w110 = fz * fy * (1.f - fx);
            float w111 = fz * fy * fx;
            #pragma unroll
            for (int c = 0; c < 3; c++) {
                const float* b = bwd + c * NN;
                float warped = w000 * b[i000] + w001 * b[i001]
                             + w010 * b[i010] + w011 * b[i011]
                             + w100 * b[i100] + w101 * b[i101]
                             + w110 * b[i110] + w111 * b[i111];
                float comp = v[c] + warped;
                accI += (double)(comp * comp);
            }
        }
    }

    double tG = block_reduce<4>(accG, red, threadIdx.x);
    double tJ = block_reduce<4>(accJ, red, threadIdx.x);
    double tI = block_reduce<4>(accI, red, threadIdx.x);
    if (threadIdx.x == 0) {
        ws[GOFF + blockIdx.x] = tG;
        ws[JOFF + blockIdx.x] = tJ;
        ws[IOFF + blockIdx.x] = tI;
    }
}

// ---------- 3) finalize ----------
__global__ __launch_bounds__(256) void finalize_kernel(const double* __restrict__ ws,
                                                       float* __restrict__ out) {
    __shared__ double red[4];
    double l = 0.0, g = 0.0, j = 0.0, inv = 0.0;
    for (int k = threadIdx.x; k < NB_LNCC; k += 256) l += ws[LOFF + k];
    for (int k = threadIdx.x; k < NB_FUSED; k += 256) {
        g   += ws[GOFF + k];
        j   += ws[JOFF + k];
        inv += ws[IOFF + k];
    }
    double tl = block_reduce<4>(l, red, threadIdx.x);
    double tg = block_reduce<4>(g, red, threadIdx.x);
    double tj = block_reduce<4>(j, red, threadIdx.x);
    double ti = block_reduce<4>(inv, red, threadIdx.x);
    if (threadIdx.x == 0) {
        double li = 1.0 - tl / (double)NN;
        if (isnan(li) || isinf(li)) li = 1.0;
        double grad = tg / (9.0 * 127.0 * 128.0 * 128.0);
        double jac  = tj / ((double)DJ * DJ * DJ);
        double iv = ti / (3.0 * (double)NN);
        if (isnan(iv)) iv = 0.0;
        else if (isinf(iv)) iv = iv > 0.0 ? 1000.0 : 0.0;
        out[0] = (float)(1.0 * li + 0.02 * grad + 0.01 * jac + 0.1 * iv);
    }
}

extern "C" void kernel_launch(void* const* d_in, const int* in_sizes, int n_in,
                              void* d_out, int out_size, void* d_ws, size_t ws_size,
                              hipStream_t stream) {
    const float* src = (const float*)d_in[0];
    const float* tgt = (const float*)d_in[1];
    const float* fwd = (const float*)d_in[2];
    const float* bwd = (const float*)d_in[3];
    double* ws = (double*)d_ws;
    float* out = (float*)d_out;

    if (ws_size >= WS_NEED) {
        float4* bwdi = (float4*)((char*)d_ws + BWDI_OFF);
        lncc_kernel<<<4096, 512, 0, stream>>>(src, tgt, bwd, bwdi, ws);
        fused2_kernel<<<NB_FUSED, 256, 0, stream>>>(fwd, bwdi, ws);
    } else {
        lncc_kernel<<<4096, 512, 0, stream>>>(src, tgt, bwd, nullptr, ws);
        fused_fallback<<<NB_FUSED, 256, 0, stream>>>(fwd, bwd, ws);
    }
    finalize_kernel<<<1, 256, 0, stream>>>(ws, out);
}

// Round 5
// 96.422 us; speedup vs baseline: 1.3227x; 1.3227x over previous
//
#include <hip/hip_runtime.h>
#include <math.h>

#define DD 128
#define HH 128
#define WW 128
#define NN (DD*HH*WW)
#define DJ 127

// workspace layout: [slots: doubles][bwd interleaved float4 volume]
#define NB_LNCC 4096
#define NB_FUSED 2048
#define LOFF 0
#define GOFF (NB_LNCC)
#define JOFF (NB_LNCC + NB_FUSED)
#define IOFF (NB_LNCC + 2*NB_FUSED)
#define NSLOTS (NB_LNCC + 3*NB_FUSED)
#define BWDI_OFF ((size_t)NSLOTS * 8)            // 16B aligned
#define WS_NEED (BWDI_OFF + (size_t)NN * 16)

// ---------- small helpers ----------
__device__ __forceinline__ double wave_reduce(double v) {
    #pragma unroll
    for (int o = 32; o > 0; o >>= 1) v += __shfl_down(v, o);
    return v;
}

template <int NWAVES>
__device__ __forceinline__ double block_reduce(double v, double* red, int tid) {
    v = wave_reduce(v);
    int wid = tid >> 6, lane = tid & 63;
    __syncthreads();
    if (lane == 0) red[wid] = v;
    __syncthreads();
    double x = 0.0;
    if (tid == 0) {
        #pragma unroll
        for (int w = 0; w < NWAVES; w++) x += red[w];
    }
    return x;
}

__device__ __forceinline__ float4 add4(float4 a, float4 b) {
    return make_float4(a.x + b.x, a.y + b.y, a.z + b.z, a.w + b.w);
}

__device__ __forceinline__ float jac_term(const float* dz_, const float* dy_, const float* dx_) {
    float a00 = 1.f + dz_[0], a01 = dy_[0], a02 = dx_[0];
    float a10 = dz_[1], a11 = 1.f + dy_[1], a12 = dx_[1];
    float a20 = dz_[2], a21 = dy_[2], a22 = 1.f + dx_[2];
    float det = a00 * (a11 * a22 - a12 * a21)
              - a01 * (a10 * a22 - a12 * a20)
              + a02 * (a10 * a21 - a11 * a20);
    if (isnan(det)) det = 0.f;
    else if (isinf(det)) det = det > 0.f ? 1000.f : -1000.f;
    float neg = -det;
    return neg > 0.f ? neg : 0.f;
}

// ---------- 1) LNCC (separable box filter, vector LDS) + embedded bwd interleave ----------
// Tile: 8^3 outputs, 12^3 window footprint. 512 threads. (round-4 version, ~25 us)
__global__ __launch_bounds__(512) void lncc_kernel(const float* __restrict__ src,
                                                   const float* __restrict__ tgt,
                                                   const float* __restrict__ bwd,
                                                   float4* __restrict__ bwdi,
                                                   double* __restrict__ ws) {
    __shared__ __align__(16) float F1[5][12 * 12 * 8];   // x-summed moments
    __shared__ __align__(16) float F2[5][12 * 8 * 8];    // xy-summed moments
    __shared__ double red[8];
    const int tid = threadIdx.x;
    const int bid = blockIdx.x;
    const int bx = (bid & 15) * 8, by = ((bid >> 4) & 15) * 8, bz = (bid >> 8) * 8;

    // ---- embedded channel-interleave of bwd (1 voxel/thread) ----
    if (bwdi) {
        int i = bid * 512 + tid;
        bwdi[i] = make_float4(bwd[i], bwd[NN + i], bwd[2 * NN + i], 0.f);
    }

    // ---- x-pass: one half-row (4 outputs) per thread, 288 tasks ----
    if (tid < 288) {
        const int h = tid & 1;
        const int row = tid >> 1;
        const int ly = row % 12, lz = row / 12;
        const int gy = by + ly - 2, gz = bz + lz - 2;
        const bool rowok = (gy >= 0 && gy < HH && gz >= 0 && gz < DD);
        const int rowbase = (gz * HH + gy) * WW;
        const int w0 = bx + h * 4 - 4;            // aligned float4 window start

        float4 lsv[3], ltv[3];
        #pragma unroll
        for (int p = 0; p < 3; p++) {
            int gx = w0 + 4 * p;
            if (rowok && gx >= 0 && gx <= WW - 4) {
                lsv[p] = *(const float4*)(src + rowbase + gx);
                ltv[p] = *(const float4*)(tgt + rowbase + gx);
            } else {
                lsv[p] = make_float4(0.f, 0.f, 0.f, 0.f);
                ltv[p] = make_float4(0.f, 0.f, 0.f, 0.f);
            }
        }
        const float* ls = (const float*)lsv;   // 12 values, static-indexed below
        const float* lt = (const float*)ltv;

        float o[5][4];
        #pragma unroll
        for (int k = 0; k < 4; k++) {
            float s1 = 0.f, t1 = 0.f, s2 = 0.f, t2 = 0.f, st = 0.f;
            #pragma unroll
            for (int d = 0; d < 5; d++) {
                float a = ls[k + d + 2], b = lt[k + d + 2];
                s1 += a; t1 += b;
                s2 = fmaf(a, a, s2); t2 = fmaf(b, b, t2); st = fmaf(a, b, st);
            }
            o[0][k] = s1; o[1][k] = t1; o[2][k] = s2; o[3][k] = t2; o[4][k] = st;
        }
        const int obase = (lz * 12 + ly) * 8 + h * 4;
        #pragma unroll
        for (int f = 0; f < 5; f++)
            *(float4*)&F1[f][obase] = make_float4(o[f][0], o[f][1], o[f][2], o[f][3]);
    }
    __syncthreads();

    // ---- y-pass: 4 outputs per thread, 192 tasks ----
    if (tid < 192) {
        const int h = tid & 1;
        const int r = tid >> 1;
        const int oy = r & 7, lz = r >> 3;
        float4 a0 = make_float4(0.f, 0.f, 0.f, 0.f), a1 = a0, a2 = a0, a3 = a0, a4 = a0;
        #pragma unroll
        for (int dy = 0; dy < 5; dy++) {
            const int j = (lz * 12 + oy + dy) * 8 + h * 4;
            a0 = add4(a0, *(const float4*)&F1[0][j]);
            a1 = add4(a1, *(const float4*)&F1[1][j]);
            a2 = add4(a2, *(const float4*)&F1[2][j]);
            a3 = add4(a3, *(const float4*)&F1[3][j]);
            a4 = add4(a4, *(const float4*)&F1[4][j]);
        }
        const int jo = (lz * 8 + oy) * 8 + h * 4;
        *(float4*)&F2[0][jo] = a0;
        *(float4*)&F2[1][jo] = a1;
        *(float4*)&F2[2][jo] = a2;
        *(float4*)&F2[3][jo] = a3;
        *(float4*)&F2[4][jo] = a4;
    }
    __syncthreads();

    // ---- z-pass + lncc: 4 voxels per thread, 128 tasks ----
    double lsum = 0.0;
    if (tid < 128) {
        const int h = tid & 1;
        const int r = tid >> 1;
        const int oy = r & 7, oz = r >> 3;
        float A[5][4];
        #pragma unroll
        for (int f = 0; f < 5; f++) { A[f][0] = A[f][1] = A[f][2] = A[f][3] = 0.f; }
        #pragma unroll
        for (int dz = 0; dz < 5; dz++) {
            const int j = ((oz + dz) * 8 + oy) * 8 + h * 4;
            #pragma unroll
            for (int f = 0; f < 5; f++) {
                float4 q = *(const float4*)&F2[f][j];
                A[f][0] += q.x; A[f][1] += q.y; A[f][2] += q.z; A[f][3] += q.w;
            }
        }
        const float inv125 = 1.f / 125.f;
        #pragma unroll
        for (int k = 0; k < 4; k++) {
            float sm = A[0][k] * inv125, tm = A[1][k] * inv125;
            float sv = A[2][k] * inv125 - sm * sm;
            float tv = A[3][k] * inv125 - tm * tm;
            float cross = A[4][k] * inv125 - sm * tm;
            float l = cross * cross / (sv * tv + 1e-5f);
            lsum += (double)l;
        }
    }
    double tot = block_reduce<8>(lsum, red, tid);
    if (tid == 0) ws[LOFF + bid] = tot;
}

// ---------- 2) fused grad + jac + inverse-consistency, 4 voxels/thread ----------
// Round-3 structure (proven 50 us) + XCD-chunked block swizzle:
// nwg=2048, 8 XCDs, round-robin dispatch => bid%8 is the XCD. Remap so each
// XCD owns a contiguous z-chunk (blocks xcd*256..xcd*256+255 = 16 z-slices):
// gather neighborhoods and z+1-slice reuse stay within one XCD's L2.
__global__ __launch_bounds__(256) void fused4_kernel(const float* __restrict__ fwd,
                                                     const float4* __restrict__ bwdi,
                                                     double* __restrict__ ws) {
    __shared__ double red[4];
    double accG = 0.0, accJ = 0.0, accI = 0.0;

    const int swz = (blockIdx.x & 7) * (NB_FUSED / 8) + (blockIdx.x >> 3);  // bijective (2048%8==0)
    const int t4 = (swz * 256 + threadIdx.x) * 4;   // base voxel (x % 4 == 0)
    const int x = t4 & 127; int rr = t4 >> 7; const int y = rr & 127; const int z = rr >> 7;
    const bool hy = (y < HH - 1), hz = (z < DD - 1);

    // per-channel: 5 x-values (float4 + next scalar), y+1 row, z+1 slice
    float av[3][5]; float4 Y4[3], Z4[3];
    #pragma unroll
    for (int c = 0; c < 3; c++) {
        const float* p = fwd + c * NN + t4;
        float4 q = *(const float4*)p;
        av[c][0] = q.x; av[c][1] = q.y; av[c][2] = q.z; av[c][3] = q.w;
        av[c][4] = (x < 124) ? p[4] : 0.f;
        Y4[c] = hy ? *(const float4*)(p + WW) : make_float4(0.f, 0.f, 0.f, 0.f);
        Z4[c] = hz ? *(const float4*)(p + WW * HH) : make_float4(0.f, 0.f, 0.f, 0.f);
    }

    #pragma unroll
    for (int j = 0; j < 4; j++) {
        const int xj = x + j;
        const bool hx = (xj < WW - 1);
        float v[3], ddx[3], ddy[3], ddz[3];
        #pragma unroll
        for (int c = 0; c < 3; c++) {
            float vv = av[c][j];
            float yv = (c == 0 ? (j == 0 ? Y4[0].x : j == 1 ? Y4[0].y : j == 2 ? Y4[0].z : Y4[0].w)
                      : c == 1 ? (j == 0 ? Y4[1].x : j == 1 ? Y4[1].y : j == 2 ? Y4[1].z : Y4[1].w)
                               : (j == 0 ? Y4[2].x : j == 1 ? Y4[2].y : j == 2 ? Y4[2].z : Y4[2].w));
            float zv = (c == 0 ? (j == 0 ? Z4[0].x : j == 1 ? Z4[0].y : j == 2 ? Z4[0].z : Z4[0].w)
                      : c == 1 ? (j == 0 ? Z4[1].x : j == 1 ? Z4[1].y : j == 2 ? Z4[1].z : Z4[1].w)
                               : (j == 0 ? Z4[2].x : j == 1 ? Z4[2].y : j == 2 ? Z4[2].z : Z4[2].w));
            v[c]   = vv;
            ddx[c] = hx ? (av[c][j + 1] - vv) : 0.f;
            ddy[c] = hy ? (yv - vv) : 0.f;
            ddz[c] = hz ? (zv - vv) : 0.f;
        }

        // grad3d L2
        float g = 0.f;
        #pragma unroll
        for (int c = 0; c < 3; c++)
            g = fmaf(ddz[c], ddz[c], fmaf(ddy[c], ddy[c], fmaf(ddx[c], ddx[c], g)));
        accG += (double)g;

        // negative Jacobian (interior only)
        if (hx && hy && hz) accJ += (double)jac_term(ddz, ddy, ddx);

        // inverse consistency via interleaved gather (8 x float4)
        {
            float cz = fminf(fmaxf((float)z + v[0], 0.f), (float)(DD - 1));
            float cy = fminf(fmaxf((float)y + v[1], 0.f), (float)(HH - 1));
            float cx = fminf(fmaxf((float)xj + v[2], 0.f), (float)(WW - 1));
            float z0f = floorf(cz), y0f = floorf(cy), x0f = floorf(cx);
            float fz = cz - z0f, fy = cy - y0f, fx = cx - x0f;
            int z0 = (int)z0f, y0 = (int)y0f, x0 = (int)x0f;
            int z1 = min(z0 + 1, DD - 1), y1 = min(y0 + 1, HH - 1), x1 = min(x0 + 1, WW - 1);
            int b00 = (z0 * HH + y0) * WW, b01 = (z0 * HH + y1) * WW;
            int b10 = (z1 * HH + y0) * WW, b11 = (z1 * HH + y1) * WW;
            float4 C000 = bwdi[b00 + x0], C001 = bwdi[b00 + x1];
            float4 C010 = bwdi[b01 + x0], C011 = bwdi[b01 + x1];
            float4 C100 = bwdi[b10 + x0], C101 = bwdi[b10 + x1];
            float4 C110 = bwdi[b11 + x0], C111 = bwdi[b11 + x1];
            float w000 = (1.f - fz) * (1.f - fy) * (1.f - fx);
            float w001 = (1.f - fz) * (1.f - fy) * fx;
            float w010 = (1.f - fz) * fy * (1.f - fx);
            float w011 = (1.f - fz) * fy * fx;
            float w100 = fz * (1.f - fy) * (1.f - fx);
            float w101 = fz * (1.f - fy) * fx;
            float w110 = fz * fy * (1.f - fx);
            float w111 = fz * fy * fx;
            float c0 = v[0] + w000 * C000.x + w001 * C001.x + w010 * C010.x + w011 * C011.x
                            + w100 * C100.x + w101 * C101.x + w110 * C110.x + w111 * C111.x;
            float c1 = v[1] + w000 * C000.y + w001 * C001.y + w010 * C010.y + w011 * C011.y
                            + w100 * C100.y + w101 * C101.y + w110 * C110.y + w111 * C111.y;
            float c2 = v[2] + w000 * C000.z + w001 * C001.z + w010 * C010.z + w011 * C011.z
                            + w100 * C100.z + w101 * C101.z + w110 * C110.z + w111 * C111.z;
            accI += (double)(c0 * c0 + c1 * c1 + c2 * c2);
        }
    }

    double tG = block_reduce<4>(accG, red, threadIdx.x);
    double tJ = block_reduce<4>(accJ, red, threadIdx.x);
    double tI = block_reduce<4>(accI, red, threadIdx.x);
    if (threadIdx.x == 0) {
        ws[GOFF + swz] = tG;
        ws[JOFF + swz] = tJ;
        ws[IOFF + swz] = tI;
    }
}

// ---------- 2b) fallback fused kernel (scalar gathers from planar bwd) ----------
__global__ __launch_bounds__(256) void fused_fallback(const float* __restrict__ fwd,
                                                      const float* __restrict__ bwd,
                                                      double* __restrict__ ws) {
    __shared__ double red[4];
    double accG = 0.0, accJ = 0.0, accI = 0.0;

    for (int idx = blockIdx.x * 256 + threadIdx.x; idx < NN; idx += gridDim.x * 256) {
        const int x = idx % WW; int r = idx / WW; const int y = r % HH; const int z = r / HH;
        const bool hx = (x < WW - 1), hy = (y < HH - 1), hz = (z < DD - 1);

        float v[3], ddx[3], ddy[3], ddz[3];
        #pragma unroll
        for (int c = 0; c < 3; c++) {
            const float* p = fwd + c * NN + idx;
            float vv = p[0];
            v[c]   = vv;
            ddx[c] = hx ? (p[1] - vv) : 0.f;
            ddy[c] = hy ? (p[WW] - vv) : 0.f;
            ddz[c] = hz ? (p[HH * WW] - vv) : 0.f;
        }
        float g = 0.f;
        #pragma unroll
        for (int c = 0; c < 3; c++)
            g = fmaf(ddz[c], ddz[c], fmaf(ddy[c], ddy[c], fmaf(ddx[c], ddx[c], g)));
        accG += (double)g;

        if (hx && hy && hz) accJ += (double)jac_term(ddz, ddy, ddx);
        {
            float cz = fminf(fmaxf((float)z + v[0], 0.f), (float)(DD - 1));
            float cy = fminf(fmaxf((float)y + v[1], 0.f), (float)(HH - 1));
            float cx = fminf(fmaxf((float)x + v[2], 0.f), (float)(WW - 1));
            float z0f = floorf(cz), y0f = floorf(cy), x0f = floorf(cx);
            float fz = cz - z0f, fy = cy - y0f, fx = cx - x0f;
            int z0 = (int)z0f, y0 = (int)y0f, x0 = (int)x0f;
            int z1 = min(z0 + 1, DD - 1), y1 = min(y0 + 1, HH - 1), x1 = min(x0 + 1, WW - 1);
            int i000 = (z0 * HH + y0) * WW + x0, i001 = (z0 * HH + y0) * WW + x1;
            int i010 = (z0 * HH + y1) * WW + x0, i011 = (z0 * HH + y1) * WW + x1;
            int i100 = (z1 * HH + y0) * WW + x0, i101 = (z1 * HH + y0) * WW + x1;
            int i110 = (z1 * HH + y1) * WW + x0, i111 = (z1 * HH + y1) * WW + x1;
            float w000 = (1.f - fz) * (1.f - fy) * (1.f - fx);
            float w001 = (1.f - fz) * (1.f - fy) * fx;
            float w010 = (1.f - fz) * fy * (1.f - fx);
            float w011 = (1.f - fz) * fy * fx;
            float w100 = fz * (1.f - fy) * (1.f - fx);
            float w101 = fz * (1.f - fy) * fx;
            float w110 = fz * fy * (1.f - fx);
            float w111 = fz * fy * fx;
            #pragma unroll
            for (int c = 0; c < 3; c++) {
                const float* b = bwd + c * NN;
                float warped = w000 * b[i000] + w001 * b[i001]
                             + w010 * b[i010] + w011 * b[i011]
                             + w100 * b[i100] + w101 * b[i101]
                             + w110 * b[i110] + w111 * b[i111];
                float comp = v[c] + warped;
                accI += (double)(comp * comp);
            }
        }
    }

    double tG = block_reduce<4>(accG, red, threadIdx.x);
    double tJ = block_reduce<4>(accJ, red, threadIdx.x);
    double tI = block_reduce<4>(accI, red, threadIdx.x);
    if (threadIdx.x == 0) {
        ws[GOFF + blockIdx.x] = tG;
        ws[JOFF + blockIdx.x] = tJ;
        ws[IOFF + blockIdx.x] = tI;
    }
}

// ---------- 3) finalize ----------
__global__ __launch_bounds__(256) void finalize_kernel(const double* __restrict__ ws,
                                                       float* __restrict__ out) {
    __shared__ double red[4];
    double l = 0.0, g = 0.0, j = 0.0, inv = 0.0;
    for (int k = threadIdx.x; k < NB_LNCC; k += 256) l += ws[LOFF + k];
    for (int k = threadIdx.x; k < NB_FUSED; k += 256) {
        g   += ws[GOFF + k];
        j   += ws[JOFF + k];
        inv += ws[IOFF + k];
    }
    double tl = block_reduce<4>(l, red, threadIdx.x);
    double tg = block_reduce<4>(g, red, threadIdx.x);
    double tj = block_reduce<4>(j, red, threadIdx.x);
    double ti = block_reduce<4>(inv, red, threadIdx.x);
    if (threadIdx.x == 0) {
        double li = 1.0 - tl / (double)NN;
        if (isnan(li) || isinf(li)) li = 1.0;
        double grad = tg / (9.0 * 127.0 * 128.0 * 128.0);
        double jac  = tj / ((double)DJ * DJ * DJ);
        double iv = ti / (3.0 * (double)NN);
        if (isnan(iv)) iv = 0.0;
        else if (isinf(iv)) iv = iv > 0.0 ? 1000.0 : 0.0;
        out[0] = (float)(1.0 * li + 0.02 * grad + 0.01 * jac + 0.1 * iv);
    }
}

extern "C" void kernel_launch(void* const* d_in, const int* in_sizes, int n_in,
                              void* d_out, int out_size, void* d_ws, size_t ws_size,
                              hipStream_t stream) {
    const float* src = (const float*)d_in[0];
    const float* tgt = (const float*)d_in[1];
    const float* fwd = (const float*)d_in[2];
    const float* bwd = (const float*)d_in[3];
    double* ws = (double*)d_ws;
    float* out = (float*)d_out;

    if (ws_size >= WS_NEED) {
        float4* bwdi = (float4*)((char*)d_ws + BWDI_OFF);
        lncc_kernel<<<4096, 512, 0, stream>>>(src, tgt, bwd, bwdi, ws);
        fused4_kernel<<<NB_FUSED, 256, 0, stream>>>(fwd, bwdi, ws);
    } else {
        lncc_kernel<<<4096, 512, 0, stream>>>(src, tgt, bwd, nullptr, ws);
        fused_fallback<<<NB_FUSED, 256, 0, stream>>>(fwd, bwd, ws);
    }
    finalize_kernel<<<1, 256, 0, stream>>>(ws, out);
}